// Round 6
// baseline (745.686 us; speedup 1.0000x reference)
//
#include <hip/hip_runtime.h>

#define NPTS 8192
#define PTS 32768

typedef unsigned short u16;
typedef __attribute__((ext_vector_type(8))) short bf16x8;
typedef __attribute__((ext_vector_type(4))) float f32x4;

__device__ __forceinline__ float lrelu(float x){ return x >= 0.f ? x : 0.1f*x; }
__device__ __forceinline__ unsigned f2bf(float x){
  unsigned u = __float_as_uint(x);
  return ((u + 0x7FFFu + ((u>>16)&1u)) >> 16);
}
__device__ __forceinline__ float bf2f(u16 h){ return __uint_as_float(((unsigned)h)<<16); }
__device__ __forceinline__ float bf_lo(unsigned u){ return __uint_as_float(u << 16); }
__device__ __forceinline__ float bf_hi(unsigned u){ return __uint_as_float(u & 0xffff0000u); }

// ---- xyz fill: fT1 stride 288 (cols 0..2 xyz, 259..287 zero);
//                fT2 stride 160 (cols 128..130 xyz, 131..159 zero) ----------
__global__ __launch_bounds__(256) void xyz_fill_kernel(
    const float* __restrict__ xyz, u16* __restrict__ fT1, u16* __restrict__ fT2){
  long g = (long)blockIdx.x*256 + threadIdx.x;
  int b = (int)(g >> 13), n = (int)(g & 8191);
  unsigned v[3];
  #pragma unroll
  for (int j = 0; j < 3; ++j) v[j] = f2bf(xyz[((long)b*3 + j)*NPTS + n]);
  u16* r1 = fT1 + g*288;
  r1[0] = (u16)v[0]; r1[1] = (u16)v[1]; r1[2] = (u16)v[2];
  #pragma unroll
  for (int j = 259; j < 264; ++j) r1[j] = 0;
  uint4 z = {0,0,0,0};
  *(uint4*)(r1 + 264) = z; *(uint4*)(r1 + 272) = z; *(uint4*)(r1 + 280) = z;
  u16* r2 = fT2 + g*160;
  uint4 u;
  u.x = v[0] | (v[1] << 16);
  u.y = v[2];
  u.z = 0; u.w = 0;
  *(uint4*)(r2 + 128) = u;
  *(uint4*)(r2 + 136) = z; *(uint4*)(r2 + 144) = z; *(uint4*)(r2 + 152) = z;
}

// ---- transpose feat [B][256][N] -> fT1 rows [g][288] cols 3..258 (bf16) ----
__global__ __launch_bounds__(256) void transpose_feat_kernel(
    const float* __restrict__ feat, u16* __restrict__ fT1){
  __shared__ float tile[64][65];
  int bx = blockIdx.x, by = blockIdx.y, bz = blockIdx.z;
  int t = threadIdx.x;
  int x = t & 63, y4 = t >> 6;
  const float* src = feat + ((long)bz*256 + by*64)*NPTS + (long)bx*64;
  #pragma unroll
  for (int i = 0; i < 16; ++i){
    int c = y4 + i*4;
    tile[c][x] = src[(long)c*NPTS + x];
  }
  __syncthreads();
  u16* dst = fT1 + ((long)bz*NPTS + (long)bx*64)*288 + 3 + by*64;
  #pragma unroll
  for (int i = 0; i < 16; ++i){
    int p = y4 + i*4;
    dst[(long)p*288 + x] = (u16)f2bf(tile[x][p]);
  }
}

// ---- weight prep: Bt[o][k] bf16, zero-padded to KP -------------------------
__global__ void prep_bt_kernel(const float* __restrict__ W, u16* __restrict__ Bt,
                               int KP, int KREAL){
  int o = blockIdx.y;
  int k = blockIdx.x*256 + threadIdx.x;
  if (k < KP)
    Bt[(long)o*KP + k] = (k < KREAL) ? (u16)f2bf(W[(long)o*KREAL + k]) : (u16)0;
}

// layer2 channel permute: our c: 0..127 feat (ref c+3), 128..130 xyz (ref c-128)
__global__ void prep_bt2_kernel(const float* __restrict__ W, u16* __restrict__ Bt){
  int o = blockIdx.y;
  int k = blockIdx.x*256 + threadIdx.x;
  if (k >= 1280) return;
  int c = k >> 3, m = k & 7;
  u16 v = 0;
  if (c < 128)      v = (u16)f2bf(W[(long)o*1048 + (c+3)*8 + m]);
  else if (c < 131) v = (u16)f2bf(W[(long)o*1048 + (c-128)*8 + m]);
  Bt[(long)o*1280 + k] = v;
}

// ---- fused PointConv v2: direct-gather + reg agg + MFMA GEMM ---------------
// Block: 64 points x 128 outs, 256 threads. S = NCH*32 (u16 stride), K = NCH*256.
template<int NCH>
__global__ __launch_bounds__(256, 2) void fused_pc2_kernel(
    const u16* __restrict__ fT, const float* __restrict__ xyz,
    const int* __restrict__ knn, const float* __restrict__ w_wn,
    const float* __restrict__ b_wn, const u16* __restrict__ Bt,
    const float* __restrict__ bias, u16* __restrict__ outp, int out_stride){
  constexpr int S = NCH*32;
  constexpr int K = NCH*256;
  __shared__ __align__(16) u16 As[64][264];      // 33792 B (chunk's 256 k-elems)
  __shared__ __align__(16) u16 Bs[2][128][80];   // 40960 B (double-buffered 64-k sub)

  int t = threadIdx.x;
  int m0 = blockIdx.x*64;
  int b = m0 >> 13;
  long bbase = (long)b << 13;
  int n0 = m0 & 8191;

  int w = t >> 6, l = t & 63, ln = l & 15, lh = l >> 4;
  int o0 = w*32;
  int pA = t >> 2, cp = t & 3;

  // Bs staging slots (8 segs per 64-elem row)
  int brow[4], bseg[4];
  #pragma unroll
  for (int j = 0; j < 4; ++j){
    int idx2 = j*256 + t;
    brow[j] = idx2 >> 3; bseg[j] = (idx2 & 7)*8;
  }

  // knn indices -> per-point row byte offsets
  unsigned offs[16];
  int idxk[16];
  {
    const int* krow = knn + (bbase + n0 + pA)*16;
    int4 q0 = ((const int4*)krow)[0];
    int4 q1 = ((const int4*)krow)[1];
    int4 q2 = ((const int4*)krow)[2];
    int4 q3 = ((const int4*)krow)[3];
    idxk[0]=q0.x; idxk[1]=q0.y; idxk[2]=q0.z; idxk[3]=q0.w;
    idxk[4]=q1.x; idxk[5]=q1.y; idxk[6]=q1.z; idxk[7]=q1.w;
    idxk[8]=q2.x; idxk[9]=q2.y; idxk[10]=q2.z; idxk[11]=q2.w;
    idxk[12]=q3.x; idxk[13]=q3.y; idxk[14]=q3.z; idxk[15]=q3.w;
    #pragma unroll
    for (int k = 0; k < 16; ++k)
      offs[k] = (unsigned)(((int)bbase + idxk[k])*S*2);
  }

  uint4 ga[16];
  auto ISSUE_GA = [&](int ch){
    #pragma unroll
    for (int k = 0; k < 16; ++k)
      ga[k] = *(const uint4*)((const char*)fT + offs[k] + ch*64 + cp*16);
  };

  uint4 bb[4];
  auto ISSUE_BB = [&](int gk){
    int c2 = gk >> 2, s2 = gk & 3;
    #pragma unroll
    for (int j = 0; j < 4; ++j)
      bb[j] = *(const uint4*)(Bt + (long)brow[j]*K + c2*256 + s2*64 + bseg[j]);
  };

  ISSUE_GA(0);
  ISSUE_BB(0);

  // wk prologue: 16 weight-net vectors for this thread's point, in regs
  uint4 wkv[16];
  {
    float cx = xyz[((long)b*3+0)*NPTS + n0 + pA];
    float cy = xyz[((long)b*3+1)*NPTS + n0 + pA];
    float cz = xyz[((long)b*3+2)*NPTS + n0 + pA];
    float wm[8][3], bm[8];
    #pragma unroll
    for (int m = 0; m < 8; ++m){
      wm[m][0] = w_wn[m*3+0]; wm[m][1] = w_wn[m*3+1]; wm[m][2] = w_wn[m*3+2];
      bm[m] = b_wn[m];
    }
    #pragma unroll
    for (int k = 0; k < 16; ++k){
      int id = idxk[k];
      float px = xyz[((long)b*3+0)*NPTS + id] - cx;
      float py = xyz[((long)b*3+1)*NPTS + id] - cy;
      float pz = xyz[((long)b*3+2)*NPTS + id] - cz;
      unsigned wv[8];
      #pragma unroll
      for (int m = 0; m < 8; ++m){
        float v = wm[m][0]*px + wm[m][1]*py + wm[m][2]*pz + bm[m];
        wv[m] = f2bf(lrelu(v));
      }
      uint4 u;
      u.x = wv[0] | (wv[1] << 16);
      u.y = wv[2] | (wv[3] << 16);
      u.z = wv[4] | (wv[5] << 16);
      u.w = wv[6] | (wv[7] << 16);
      wkv[k] = u;
    }
  }

  f32x4 acc[4][2];
  #pragma unroll
  for (int i = 0; i < 4; ++i)
    #pragma unroll
    for (int j = 0; j < 2; ++j) acc[i][j] = (f32x4){0.f,0.f,0.f,0.f};

  // phase A: consume ga -> 8x8 outer-product agg in regs -> As[pA][cp*64..+64]
  auto PHASE_A = [&](){
    float2 a2[8][4];
    #pragma unroll
    for (int c = 0; c < 8; ++c)
      #pragma unroll
      for (int j = 0; j < 4; ++j) a2[c][j] = make_float2(0.f, 0.f);
    #pragma unroll
    for (int k = 0; k < 16; ++k){
      uint4 v = ga[k];
      float fv[8];
      fv[0] = bf_lo(v.x); fv[1] = bf_hi(v.x);
      fv[2] = bf_lo(v.y); fv[3] = bf_hi(v.y);
      fv[4] = bf_lo(v.z); fv[5] = bf_hi(v.z);
      fv[6] = bf_lo(v.w); fv[7] = bf_hi(v.w);
      uint4 u = wkv[k];
      float2 w0 = make_float2(bf_lo(u.x), bf_hi(u.x));
      float2 w1 = make_float2(bf_lo(u.y), bf_hi(u.y));
      float2 w2 = make_float2(bf_lo(u.z), bf_hi(u.z));
      float2 w3 = make_float2(bf_lo(u.w), bf_hi(u.w));
      #pragma unroll
      for (int c = 0; c < 8; ++c){
        float fc = fv[c];
        a2[c][0].x += fc*w0.x; a2[c][0].y += fc*w0.y;
        a2[c][1].x += fc*w1.x; a2[c][1].y += fc*w1.y;
        a2[c][2].x += fc*w2.x; a2[c][2].y += fc*w2.y;
        a2[c][3].x += fc*w3.x; a2[c][3].y += fc*w3.y;
      }
    }
    #pragma unroll
    for (int c = 0; c < 8; ++c){
      uint4 o;
      o.x = f2bf(a2[c][0].x) | (f2bf(a2[c][0].y) << 16);
      o.y = f2bf(a2[c][1].x) | (f2bf(a2[c][1].y) << 16);
      o.z = f2bf(a2[c][2].x) | (f2bf(a2[c][2].y) << 16);
      o.w = f2bf(a2[c][3].x) | (f2bf(a2[c][3].y) << 16);
      *(uint4*)&As[pA][cp*64 + c*8] = o;
    }
  };

  PHASE_A();            // chunk 0
  ISSUE_GA(1);

  for (int ch = 0; ch < NCH; ++ch){
    __syncthreads();    // As(ch) visible; prev chunk's reads done
    #pragma unroll
    for (int sub = 0; sub < 4; ++sub){
      int par = sub & 1;
      #pragma unroll
      for (int j = 0; j < 4; ++j)
        *(uint4*)&Bs[par][brow[j]][bseg[j]] = bb[j];
      int gk = ch*4 + sub + 1;
      if (gk > NCH*4 - 1) gk = NCH*4 - 1;
      ISSUE_BB(gk);
      __syncthreads();  // Bs[par] ready
      #pragma unroll
      for (int kk = 0; kk < 2; ++kk){
        int koff = sub*64 + kk*32 + lh*8;
        bf16x8 af[4], bfr[2];
        #pragma unroll
        for (int fm = 0; fm < 4; ++fm)
          af[fm] = *(const bf16x8*)&As[fm*16 + ln][koff];
        #pragma unroll
        for (int fn = 0; fn < 2; ++fn)
          bfr[fn] = *(const bf16x8*)&Bs[par][o0 + fn*16 + ln][kk*32 + lh*8];
        #pragma unroll
        for (int fm = 0; fm < 4; ++fm)
          #pragma unroll
          for (int fn = 0; fn < 2; ++fn)
            acc[fm][fn] = __builtin_amdgcn_mfma_f32_16x16x32_bf16(af[fm], bfr[fn], acc[fm][fn], 0, 0, 0);
      }
    }
    __syncthreads();    // all As/Bs reads of this chunk done
    if (ch + 1 < NCH){
      PHASE_A();        // consumes ga(ch+1), writes As
      if (ch + 2 < NCH) ISSUE_GA(ch + 2);
    }
  }

  // ---- epilogue (Cs aliases As) ----
  u16* Cs = (u16*)As;
  float bia[2] = { bias[o0 + ln], bias[o0 + 16 + ln] };
  #pragma unroll
  for (int fm = 0; fm < 4; ++fm)
    #pragma unroll
    for (int fn = 0; fn < 2; ++fn)
      #pragma unroll
      for (int r = 0; r < 4; ++r){
        int row = fm*16 + lh*4 + r;
        int col = o0 + fn*16 + ln;
        Cs[row*128 + col] = (u16)f2bf(lrelu(acc[fm][fn][r] + bia[fn]));
      }
  __syncthreads();
  int r2 = t >> 2, s2 = t & 3;
  u16* dst = outp + (long)(m0 + r2)*out_stride + s2*32;
  #pragma unroll
  for (int q = 0; q < 4; ++q)
    *(uint4*)(dst + q*8) = *(uint4*)&Cs[r2*128 + s2*32 + q*8];
}

// ---- MFMA GEMM (round-3 verified): used for mlp1/mlp2 ----------------------
template<int BN, int OUTMODE>
__global__ __launch_bounds__(256) void mfma_lin_kernel(
    const u16* __restrict__ A, const u16* __restrict__ Bt,
    const float* __restrict__ bias, void* __restrict__ outp,
    int K, long chunk_base, int out_stride){
  __shared__ __align__(16) u16 As[64][72];
  __shared__ __align__(16) u16 Bs[BN][72];
  constexpr int FM = (BN == 128) ? 4 : 2;
  int t = threadIdx.x;
  int w = t >> 6, l = t & 63;
  int ln = l & 15, lh = l >> 4;
  int m0 = blockIdx.x * 64;
  int MOFF = (BN == 128) ? 0 : (w >> 1)*32;
  int o0   = (BN == 128) ? w*32 : (w & 1)*32;
  int srow = t >> 3;
  int scol = (t & 7) * 8;

  f32x4 acc[FM][2];
  #pragma unroll
  for (int i = 0; i < FM; ++i)
    #pragma unroll
    for (int j = 0; j < 2; ++j) acc[i][j] = (f32x4){0.f,0.f,0.f,0.f};

  int nkc = K >> 6;
  for (int kc = 0; kc < nkc; ++kc){
    uint4 a0 = *(const uint4*)(A + (long)(m0 + srow)*K      + kc*64 + scol);
    uint4 a1 = *(const uint4*)(A + (long)(m0 + srow + 32)*K + kc*64 + scol);
    uint4 bv[BN/32];
    #pragma unroll
    for (int r = 0; r < BN/32; ++r)
      bv[r] = *(const uint4*)(Bt + (long)(srow + r*32)*K + kc*64 + scol);
    __syncthreads();
    *(uint4*)&As[srow][scol]      = a0;
    *(uint4*)&As[srow + 32][scol] = a1;
    #pragma unroll
    for (int r = 0; r < BN/32; ++r)
      *(uint4*)&Bs[srow + r*32][scol] = bv[r];
    __syncthreads();
    #pragma unroll
    for (int kk = 0; kk < 2; ++kk){
      int koff = kk*32 + lh*8;
      bf16x8 af[FM], bfr[2];
      #pragma unroll
      for (int fm = 0; fm < FM; ++fm)
        af[fm] = *(const bf16x8*)&As[MOFF + fm*16 + ln][koff];
      #pragma unroll
      for (int fn = 0; fn < 2; ++fn)
        bfr[fn] = *(const bf16x8*)&Bs[o0 + fn*16 + ln][koff];
      #pragma unroll
      for (int fm = 0; fm < FM; ++fm)
        #pragma unroll
        for (int fn = 0; fn < 2; ++fn)
          acc[fm][fn] = __builtin_amdgcn_mfma_f32_16x16x32_bf16(af[fm], bfr[fn], acc[fm][fn], 0, 0, 0);
    }
    __syncthreads();
  }

  if (OUTMODE == 0){
    __shared__ u16 Cs[64*128];
    float bia[2];
    #pragma unroll
    for (int fn = 0; fn < 2; ++fn) bia[fn] = bias[o0 + fn*16 + ln];
    __syncthreads();
    #pragma unroll
    for (int fm = 0; fm < FM; ++fm)
      #pragma unroll
      for (int fn = 0; fn < 2; ++fn)
        #pragma unroll
        for (int r = 0; r < 4; ++r){
          int row = MOFF + fm*16 + lh*4 + r;
          int col = o0 + fn*16 + ln;
          Cs[row*128 + col] = (u16)f2bf(lrelu(acc[fm][fn][r] + bia[fn]));
        }
    __syncthreads();
    int r2 = t >> 2, s2 = t & 3;
    u16* dst = (u16*)outp + (chunk_base + m0 + r2)*(long)out_stride + s2*32;
    #pragma unroll
    for (int q = 0; q < 4; ++q)
      *(uint4*)(dst + q*8) = *(uint4*)&Cs[r2*128 + s2*32 + q*8];
  } else {
    float* outf = (float*)outp;
    #pragma unroll
    for (int fm = 0; fm < FM; ++fm)
      #pragma unroll
      for (int fn = 0; fn < 2; ++fn){
        long gp = chunk_base + m0 + MOFF + fm*16 + lh*4;
        int bb = (int)(gp >> 13), nn = (int)(gp & 8191);
        int col = o0 + fn*16 + ln;
        float bia = bias[col];
        float4 v;
        v.x = lrelu(acc[fm][fn][0] + bia);
        v.y = lrelu(acc[fm][fn][1] + bia);
        v.z = lrelu(acc[fm][fn][2] + bia);
        v.w = lrelu(acc[fm][fn][3] + bia);
        *(float4*)(outf + ((long)(bb*64 + col) << 13) + nn) = v;
      }
  }
}

// ---- flow head: [3][64] @ f ------------------------------------------------
__global__ __launch_bounds__(256) void flow_kernel(
    const float* __restrict__ f, const float* __restrict__ W,
    const float* __restrict__ bias, float* __restrict__ flow){
  long g = (long)blockIdx.x*256 + threadIdx.x;
  int b = (int)(g >> 13), n = (int)(g & 8191);
  float a0 = bias[0], a1 = bias[1], a2 = bias[2];
  const float* fb = f + (long)b*64*NPTS + n;
  #pragma unroll
  for (int c = 0; c < 64; ++c){
    float v = fb[(long)c*NPTS];
    a0 += v * W[c];
    a1 += v * W[64 + c];
    a2 += v * W[128 + c];
  }
  flow[((long)b*3 + 0)*NPTS + n] = a0;
  flow[((long)b*3 + 1)*NPTS + n] = a1;
  flow[((long)b*3 + 2)*NPTS + n] = a2;
}

extern "C" void kernel_launch(void* const* d_in, const int* in_sizes, int n_in,
                              void* d_out, int out_size, void* d_ws, size_t ws_size,
                              hipStream_t stream){
  const float* xyz    = (const float*)d_in[0];
  const float* feat   = (const float*)d_in[1];
  const int*   knn    = (const int*)  d_in[2];
  const float* w_wn1  = (const float*)d_in[3];
  const float* b_wn1  = (const float*)d_in[4];
  const float* w_lin1 = (const float*)d_in[5];
  const float* b_lin1 = (const float*)d_in[6];
  const float* w_wn2  = (const float*)d_in[7];
  const float* b_wn2  = (const float*)d_in[8];
  const float* w_lin2 = (const float*)d_in[9];
  const float* b_lin2 = (const float*)d_in[10];
  const float* w_mlp1 = (const float*)d_in[11];
  const float* b_mlp1 = (const float*)d_in[12];
  const float* w_mlp2 = (const float*)d_in[13];
  const float* b_mlp2 = (const float*)d_in[14];
  const float* w_last = (const float*)d_in[15];
  const float* b_last = (const float*)d_in[16];
  float* out = (float*)d_out;

  char* p = (char*)d_ws;
  auto carve = [&](size_t bytes)->char*{
    char* r = p; p += (bytes + 255) & ~(size_t)255; return r;
  };
  u16* fT1   = (u16*)carve((size_t)PTS*288*2);
  u16* fT2   = (u16*)carve((size_t)PTS*160*2);
  u16* Bt1   = (u16*)carve((size_t)128*2304*2);
  u16* Bt2   = (u16*)carve((size_t)128*1280*2);
  u16* Bm1   = (u16*)carve((size_t)128*128*2);
  u16* Bm2   = (u16*)carve((size_t)64*128*2);
  u16* feat2 = (u16*)carve((size_t)PTS*128*2);
  u16* h1    = (u16*)carve((size_t)PTS*128*2);

  xyz_fill_kernel<<<PTS/256, 256, 0, stream>>>(xyz, fT1, fT2);
  transpose_feat_kernel<<<dim3(128,4,4), 256, 0, stream>>>(feat, fT1);
  prep_bt_kernel<<<dim3(9,128), 256, 0, stream>>>(w_lin1, Bt1, 2304, 2072);
  prep_bt2_kernel<<<dim3(5,128), 256, 0, stream>>>(w_lin2, Bt2);
  prep_bt_kernel<<<dim3(1,128), 256, 0, stream>>>(w_mlp1, Bm1, 128, 128);
  prep_bt_kernel<<<dim3(1,64),  256, 0, stream>>>(w_mlp2, Bm2, 128, 128);

  // fused pointconv layers (direct-gather v2)
  fused_pc2_kernel<9><<<PTS/64, 256, 0, stream>>>(fT1, xyz, knn, w_wn1, b_wn1, Bt1, b_lin1, fT2, 160);
  fused_pc2_kernel<5><<<PTS/64, 256, 0, stream>>>(fT2, xyz, knn, w_wn2, b_wn2, Bt2, b_lin2, feat2, 128);

  // mlp1 128->128, mlp2 128->64 (f output), flow head
  mfma_lin_kernel<128,0><<<PTS/64, 256, 0, stream>>>(feat2, Bm1, b_mlp1, h1, 128, 0, 128);
  mfma_lin_kernel<64,1><<<PTS/64, 256, 0, stream>>>(h1, Bm2, b_mlp2, out, 128, 0, 0);
  flow_kernel<<<PTS/256, 256, 0, stream>>>(out, w_last, b_last, out + (long)4*64*NPTS);
}

// Round 7
// 330.779 us; speedup vs baseline: 2.2543x; 2.2543x over previous
//
#include <hip/hip_runtime.h>

#define NPTS 8192
#define PTS 32768

typedef unsigned short u16;
typedef __attribute__((ext_vector_type(8))) short bf16x8;
typedef __attribute__((ext_vector_type(4))) float f32x4;

__device__ __forceinline__ float lrelu(float x){ return x >= 0.f ? x : 0.1f*x; }
__device__ __forceinline__ unsigned f2bf(float x){
  unsigned u = __float_as_uint(x);
  return ((u + 0x7FFFu + ((u>>16)&1u)) >> 16);
}
__device__ __forceinline__ float bf2f(u16 h){ return __uint_as_float(((unsigned)h)<<16); }

// ---- xyz fill: fT1 cols 0..2 + zero pad 259..263; fT2 cols 128..135 -------
__global__ __launch_bounds__(256) void xyz_fill_kernel(
    const float* __restrict__ xyz, u16* __restrict__ fT1, u16* __restrict__ fT2){
  long g = (long)blockIdx.x*256 + threadIdx.x;
  int b = (int)(g >> 13), n = (int)(g & 8191);
  unsigned v[3];
  #pragma unroll
  for (int j = 0; j < 3; ++j) v[j] = f2bf(xyz[((long)b*3 + j)*NPTS + n]);
  fT1[g*264 + 0] = (u16)v[0]; fT1[g*264 + 1] = (u16)v[1]; fT1[g*264 + 2] = (u16)v[2];
  #pragma unroll
  for (int j = 259; j < 264; ++j) fT1[g*264 + j] = 0;
  uint4 u;
  u.x = v[0] | (v[1] << 16);
  u.y = v[2];
  u.z = 0; u.w = 0;
  *(uint4*)(fT2 + g*136 + 128) = u;
}

// ---- transpose feat [B][256][N] -> fT1 rows [g][264] cols 3..258 (bf16) ----
__global__ __launch_bounds__(256) void transpose_feat_kernel(
    const float* __restrict__ feat, u16* __restrict__ fT1){
  __shared__ float tile[64][65];
  int bx = blockIdx.x, by = blockIdx.y, bz = blockIdx.z;
  int t = threadIdx.x;
  int x = t & 63, y4 = t >> 6;
  const float* src = feat + ((long)bz*256 + by*64)*NPTS + (long)bx*64;
  #pragma unroll
  for (int i = 0; i < 16; ++i){
    int c = y4 + i*4;
    tile[c][x] = src[(long)c*NPTS + x];
  }
  __syncthreads();
  u16* dst = fT1 + ((long)bz*NPTS + (long)bx*64)*264 + 3 + by*64;
  #pragma unroll
  for (int i = 0; i < 16; ++i){
    int p = y4 + i*4;
    dst[(long)p*264 + x] = (u16)f2bf(tile[x][p]);
  }
}

// ---- weight prep: Bt[o][k] bf16, zero-padded to KP -------------------------
__global__ void prep_bt_kernel(const float* __restrict__ W, u16* __restrict__ Bt,
                               int KP, int KREAL){
  int o = blockIdx.y;
  int k = blockIdx.x*256 + threadIdx.x;
  if (k < KP)
    Bt[(long)o*KP + k] = (k < KREAL) ? (u16)f2bf(W[(long)o*KREAL + k]) : (u16)0;
}

// layer2 channel permute: our c: 0..127 feat (ref c+3), 128..130 xyz (ref c-128)
__global__ void prep_bt2_kernel(const float* __restrict__ W, u16* __restrict__ Bt){
  int o = blockIdx.y;
  int k = blockIdx.x*256 + threadIdx.x;
  if (k >= 1088) return;
  int c = k >> 3, m = k & 7;
  u16 v = 0;
  if (c < 128)      v = (u16)f2bf(W[(long)o*1048 + (c+3)*8 + m]);
  else if (c < 131) v = (u16)f2bf(W[(long)o*1048 + (c-128)*8 + m]);
  Bt[(long)o*1088 + k] = v;
}

// ---- fused PointConv: gather + weightnet-agg + MFMA GEMM -------------------
// Block: 64 points x 128 outs. S = fT row stride (u16), K = S*8, NCH = S/8.
// XCD-swizzled blockIdx: each XCD works a contiguous point range (one batch
// half) so the per-batch gather table stays L2-resident across all NCH passes.
template<int S>
__global__ __launch_bounds__(256, 2) void fused_pc_kernel(
    const u16* __restrict__ fT, const float* __restrict__ xyz,
    const int* __restrict__ knn, const float* __restrict__ w_wn,
    const float* __restrict__ b_wn, const u16* __restrict__ Bt,
    const float* __restrict__ bias, u16* __restrict__ outp, int out_stride){
  constexpr int K   = S*8;
  constexpr int NCH = S/8;
  __shared__ __align__(16) u16   As[64][72];     //  9216 B
  __shared__ __align__(16) u16   Bs[128][72];    // 18432 B
  __shared__ __align__(16) float fst[64*140];    // 35840 B (row stride 140)
  __shared__ __align__(16) u16   wk2[64][16][8]; // 16384 B  (k swizzled +p)
  // total 79872 B -> 2 blocks/CU

  int t = threadIdx.x;
  // bijective XCD swizzle (nwg=512, 8 XCDs): XCD x gets blocks [x*64, x*64+64)
  int cpx = (int)(gridDim.x >> 3);
  int swz = (blockIdx.x & 7)*cpx + (blockIdx.x >> 3);
  int m0 = swz*64;
  int b = m0 >> 13;
  long bbase = (long)b << 13;
  int n0 = m0 & 8191;

  int w = t >> 6, l = t & 63;
  int ln = l & 15, lh = l >> 4;
  int o0 = w*32;

  // ---- staging identity: point p = lane, k-quad kb = wave ----
  int p = l, kb = w;
  int4 iv = *(const int4*)(knn + ((long)(bbase + n0 + p))*16 + kb*4);
  int idxs[4] = {iv.x, iv.y, iv.z, iv.w};

  // ---- wk compute -> wk2[p][(k+p)&15][m] (bf16) ----
  {
    float cx = xyz[((long)b*3+0)*NPTS + n0 + p];
    float cy = xyz[((long)b*3+1)*NPTS + n0 + p];
    float cz = xyz[((long)b*3+2)*NPTS + n0 + p];
    float wm[8][3], bm[8];
    #pragma unroll
    for (int m = 0; m < 8; ++m){
      wm[m][0] = w_wn[m*3+0]; wm[m][1] = w_wn[m*3+1]; wm[m][2] = w_wn[m*3+2];
      bm[m] = b_wn[m];
    }
    #pragma unroll
    for (int j = 0; j < 4; ++j){
      int k = kb*4 + j;
      int idx = idxs[j];
      float px = xyz[((long)b*3+0)*NPTS + idx] - cx;
      float py = xyz[((long)b*3+1)*NPTS + idx] - cy;
      float pz = xyz[((long)b*3+2)*NPTS + idx] - cz;
      unsigned wv[8];
      #pragma unroll
      for (int m = 0; m < 8; ++m){
        float v = wm[m][0]*px + wm[m][1]*py + wm[m][2]*pz + bm[m];
        wv[m] = f2bf(lrelu(v));
      }
      uint4 u;
      u.x = wv[0] | (wv[1] << 16);
      u.y = wv[2] | (wv[3] << 16);
      u.z = wv[4] | (wv[5] << 16);
      u.w = wv[6] | (wv[7] << 16);
      *(uint4*)&wk2[p][(k + p) & 15][0] = u;
    }
  }

  // ---- prefetch chunk 0 gathers ----
  uint4 ga[4];
  #pragma unroll
  for (int j = 0; j < 4; ++j)
    ga[j] = *(const uint4*)(fT + (bbase + idxs[j])*(long)S + 0*8);

  // ---- phase-A identity: point pA = w*16 + (l>>2), channel pair cp = l&3 ---
  int pA = w*16 + (l >> 2), cp = l & 3;

  f32x4 acc[4][2];
  #pragma unroll
  for (int i = 0; i < 4; ++i)
    #pragma unroll
    for (int j = 0; j < 2; ++j) acc[i][j] = (f32x4){0.f,0.f,0.f,0.f};

  for (int ch = 0; ch < NCH; ++ch){
    // ---- stage prefetched gather regs -> LDS (f32) ----
    #pragma unroll
    for (int j = 0; j < 4; ++j){
      int k = kb*4 + j;
      uint4 v = ga[j];
      f32x4 lo, hi;
      lo[0] = bf2f((u16)(v.x & 0xffff)); lo[1] = bf2f((u16)(v.x >> 16));
      lo[2] = bf2f((u16)(v.y & 0xffff)); lo[3] = bf2f((u16)(v.y >> 16));
      hi[0] = bf2f((u16)(v.z & 0xffff)); hi[1] = bf2f((u16)(v.z >> 16));
      hi[2] = bf2f((u16)(v.w & 0xffff)); hi[3] = bf2f((u16)(v.w >> 16));
      *(f32x4*)&fst[p*140 + k*8 + 0] = lo;
      *(f32x4*)&fst[p*140 + k*8 + 4] = hi;
    }
    // ---- stage Bt chunk [128][64] (L2-hot, direct) ----
    #pragma unroll
    for (int j = 0; j < 4; ++j){
      int idx2 = j*256 + t;
      int o = idx2 >> 3, seg = (idx2 & 7)*8;
      *(uint4*)&Bs[o][seg] = *(const uint4*)(Bt + (long)o*K + ch*64 + seg);
    }
    __syncthreads();

    // ---- issue next chunk's gathers (latency hidden under phaseA+MFMA) ----
    if (ch + 1 < NCH){
      #pragma unroll
      for (int j = 0; j < 4; ++j)
        ga[j] = *(const uint4*)(fT + (bbase + idxs[j])*(long)S + (ch+1)*8);
    }

    // ---- phase A: agg chunk -> As. thread = (pA, cp), m=0..7 in regs ----
    {
      float a0[8], a1[8];
      #pragma unroll
      for (int m = 0; m < 8; ++m){ a0[m] = 0.f; a1[m] = 0.f; }
      #pragma unroll
      for (int k = 0; k < 16; ++k){
        bf16x8 wv = *(const bf16x8*)&wk2[pA][(k + pA) & 15][0];
        const float* fr = &fst[pA*140 + k*8 + cp*2];
        float f0 = fr[0], f1 = fr[1];
        #pragma unroll
        for (int m = 0; m < 8; ++m){
          float wf = bf2f((u16)wv[m]);
          a0[m] += f0*wf;
          a1[m] += f1*wf;
        }
      }
      uint4 u0, u1;
      u0.x = f2bf(a0[0]) | (f2bf(a0[1]) << 16);
      u0.y = f2bf(a0[2]) | (f2bf(a0[3]) << 16);
      u0.z = f2bf(a0[4]) | (f2bf(a0[5]) << 16);
      u0.w = f2bf(a0[6]) | (f2bf(a0[7]) << 16);
      u1.x = f2bf(a1[0]) | (f2bf(a1[1]) << 16);
      u1.y = f2bf(a1[2]) | (f2bf(a1[3]) << 16);
      u1.z = f2bf(a1[4]) | (f2bf(a1[5]) << 16);
      u1.w = f2bf(a1[6]) | (f2bf(a1[7]) << 16);
      *(uint4*)&As[pA][cp*16 + 0] = u0;
      *(uint4*)&As[pA][cp*16 + 8] = u1;
    }
    __syncthreads();

    // ---- MFMA on the chunk ----
    #pragma unroll
    for (int kk = 0; kk < 2; ++kk){
      int koff = kk*32 + lh*8;
      bf16x8 af[4], bfr[2];
      #pragma unroll
      for (int fm = 0; fm < 4; ++fm)
        af[fm] = *(const bf16x8*)&As[fm*16 + ln][koff];
      #pragma unroll
      for (int fn = 0; fn < 2; ++fn)
        bfr[fn] = *(const bf16x8*)&Bs[o0 + fn*16 + ln][koff];
      #pragma unroll
      for (int fm = 0; fm < 4; ++fm)
        #pragma unroll
        for (int fn = 0; fn < 2; ++fn)
          acc[fm][fn] = __builtin_amdgcn_mfma_f32_16x16x32_bf16(af[fm], bfr[fn], acc[fm][fn], 0, 0, 0);
    }
    __syncthreads();
  }

  // ---- epilogue (Cs aliases fst) ----
  u16* Cs = (u16*)fst;
  float bia[2] = { bias[o0 + ln], bias[o0 + 16 + ln] };
  #pragma unroll
  for (int fm = 0; fm < 4; ++fm)
    #pragma unroll
    for (int fn = 0; fn < 2; ++fn)
      #pragma unroll
      for (int r = 0; r < 4; ++r){
        int row = fm*16 + lh*4 + r;
        int col = o0 + fn*16 + ln;
        Cs[row*128 + col] = (u16)f2bf(lrelu(acc[fm][fn][r] + bia[fn]));
      }
  __syncthreads();
  int r2 = t >> 2, s2 = t & 3;
  u16* dst = outp + (long)(m0 + r2)*out_stride + s2*32;
  #pragma unroll
  for (int q = 0; q < 4; ++q)
    *(uint4*)(dst + q*8) = *(uint4*)&Cs[r2*128 + s2*32 + q*8];
}

// ---- MFMA GEMM (round-3 verified): used for mlp1/mlp2 ----------------------
template<int BN, int OUTMODE>
__global__ __launch_bounds__(256) void mfma_lin_kernel(
    const u16* __restrict__ A, const u16* __restrict__ Bt,
    const float* __restrict__ bias, void* __restrict__ outp,
    int K, long chunk_base, int out_stride){
  __shared__ __align__(16) u16 As[64][72];
  __shared__ __align__(16) u16 Bs[BN][72];
  constexpr int FM = (BN == 128) ? 4 : 2;
  int t = threadIdx.x;
  int w = t >> 6, l = t & 63;
  int ln = l & 15, lh = l >> 4;
  int m0 = blockIdx.x * 64;
  int MOFF = (BN == 128) ? 0 : (w >> 1)*32;
  int o0   = (BN == 128) ? w*32 : (w & 1)*32;
  int srow = t >> 3;
  int scol = (t & 7) * 8;

  f32x4 acc[FM][2];
  #pragma unroll
  for (int i = 0; i < FM; ++i)
    #pragma unroll
    for (int j = 0; j < 2; ++j) acc[i][j] = (f32x4){0.f,0.f,0.f,0.f};

  int nkc = K >> 6;
  for (int kc = 0; kc < nkc; ++kc){
    uint4 a0 = *(const uint4*)(A + (long)(m0 + srow)*K      + kc*64 + scol);
    uint4 a1 = *(const uint4*)(A + (long)(m0 + srow + 32)*K + kc*64 + scol);
    uint4 bv[BN/32];
    #pragma unroll
    for (int r = 0; r < BN/32; ++r)
      bv[r] = *(const uint4*)(Bt + (long)(srow + r*32)*K + kc*64 + scol);
    __syncthreads();
    *(uint4*)&As[srow][scol]      = a0;
    *(uint4*)&As[srow + 32][scol] = a1;
    #pragma unroll
    for (int r = 0; r < BN/32; ++r)
      *(uint4*)&Bs[srow + r*32][scol] = bv[r];
    __syncthreads();
    #pragma unroll
    for (int kk = 0; kk < 2; ++kk){
      int koff = kk*32 + lh*8;
      bf16x8 af[FM], bfr[2];
      #pragma unroll
      for (int fm = 0; fm < FM; ++fm)
        af[fm] = *(const bf16x8*)&As[MOFF + fm*16 + ln][koff];
      #pragma unroll
      for (int fn = 0; fn < 2; ++fn)
        bfr[fn] = *(const bf16x8*)&Bs[o0 + fn*16 + ln][koff];
      #pragma unroll
      for (int fm = 0; fm < FM; ++fm)
        #pragma unroll
        for (int fn = 0; fn < 2; ++fn)
          acc[fm][fn] = __builtin_amdgcn_mfma_f32_16x16x32_bf16(af[fm], bfr[fn], acc[fm][fn], 0, 0, 0);
    }
    __syncthreads();
  }

  if (OUTMODE == 0){
    __shared__ u16 Cs[64*128];
    float bia[2];
    #pragma unroll
    for (int fn = 0; fn < 2; ++fn) bia[fn] = bias[o0 + fn*16 + ln];
    __syncthreads();
    #pragma unroll
    for (int fm = 0; fm < FM; ++fm)
      #pragma unroll
      for (int fn = 0; fn < 2; ++fn)
        #pragma unroll
        for (int r = 0; r < 4; ++r){
          int row = MOFF + fm*16 + lh*4 + r;
          int col = o0 + fn*16 + ln;
          Cs[row*128 + col] = (u16)f2bf(lrelu(acc[fm][fn][r] + bia[fn]));
        }
    __syncthreads();
    int r2 = t >> 2, s2 = t & 3;
    u16* dst = (u16*)outp + (chunk_base + m0 + r2)*(long)out_stride + s2*32;
    #pragma unroll
    for (int q = 0; q < 4; ++q)
      *(uint4*)(dst + q*8) = *(uint4*)&Cs[r2*128 + s2*32 + q*8];
  } else {
    float* outf = (float*)outp;
    #pragma unroll
    for (int fm = 0; fm < FM; ++fm)
      #pragma unroll
      for (int fn = 0; fn < 2; ++fn){
        long gp = chunk_base + m0 + MOFF + fm*16 + lh*4;
        int bb = (int)(gp >> 13), nn = (int)(gp & 8191);
        int col = o0 + fn*16 + ln;
        float bia = bias[col];
        float4 v;
        v.x = lrelu(acc[fm][fn][0] + bia);
        v.y = lrelu(acc[fm][fn][1] + bia);
        v.z = lrelu(acc[fm][fn][2] + bia);
        v.w = lrelu(acc[fm][fn][3] + bia);
        *(float4*)(outf + ((long)(bb*64 + col) << 13) + nn) = v;
      }
  }
}

// ---- flow head: [3][64] @ f ------------------------------------------------
__global__ __launch_bounds__(256) void flow_kernel(
    const float* __restrict__ f, const float* __restrict__ W,
    const float* __restrict__ bias, float* __restrict__ flow){
  long g = (long)blockIdx.x*256 + threadIdx.x;
  int b = (int)(g >> 13), n = (int)(g & 8191);
  float a0 = bias[0], a1 = bias[1], a2 = bias[2];
  const float* fb = f + (long)b*64*NPTS + n;
  #pragma unroll
  for (int c = 0; c < 64; ++c){
    float v = fb[(long)c*NPTS];
    a0 += v * W[c];
    a1 += v * W[64 + c];
    a2 += v * W[128 + c];
  }
  flow[((long)b*3 + 0)*NPTS + n] = a0;
  flow[((long)b*3 + 1)*NPTS + n] = a1;
  flow[((long)b*3 + 2)*NPTS + n] = a2;
}

extern "C" void kernel_launch(void* const* d_in, const int* in_sizes, int n_in,
                              void* d_out, int out_size, void* d_ws, size_t ws_size,
                              hipStream_t stream){
  const float* xyz    = (const float*)d_in[0];
  const float* feat   = (const float*)d_in[1];
  const int*   knn    = (const int*)  d_in[2];
  const float* w_wn1  = (const float*)d_in[3];
  const float* b_wn1  = (const float*)d_in[4];
  const float* w_lin1 = (const float*)d_in[5];
  const float* b_lin1 = (const float*)d_in[6];
  const float* w_wn2  = (const float*)d_in[7];
  const float* b_wn2  = (const float*)d_in[8];
  const float* w_lin2 = (const float*)d_in[9];
  const float* b_lin2 = (const float*)d_in[10];
  const float* w_mlp1 = (const float*)d_in[11];
  const float* b_mlp1 = (const float*)d_in[12];
  const float* w_mlp2 = (const float*)d_in[13];
  const float* b_mlp2 = (const float*)d_in[14];
  const float* w_last = (const float*)d_in[15];
  const float* b_last = (const float*)d_in[16];
  float* out = (float*)d_out;

  char* p = (char*)d_ws;
  auto carve = [&](size_t bytes)->char*{
    char* r = p; p += (bytes + 255) & ~(size_t)255; return r;
  };
  u16* fT1   = (u16*)carve((size_t)PTS*264*2);
  u16* fT2   = (u16*)carve((size_t)PTS*136*2);
  u16* Bt1   = (u16*)carve((size_t)128*2112*2);
  u16* Bt2   = (u16*)carve((size_t)128*1088*2);
  u16* Bm1   = (u16*)carve((size_t)128*128*2);
  u16* Bm2   = (u16*)carve((size_t)64*128*2);
  u16* feat2 = (u16*)carve((size_t)PTS*128*2);
  u16* h1    = (u16*)carve((size_t)PTS*128*2);

  xyz_fill_kernel<<<PTS/256, 256, 0, stream>>>(xyz, fT1, fT2);
  transpose_feat_kernel<<<dim3(128,4,4), 256, 0, stream>>>(feat, fT1);
  prep_bt_kernel<<<dim3(9,128), 256, 0, stream>>>(w_lin1, Bt1, 2112, 2072);
  prep_bt2_kernel<<<dim3(5,128), 256, 0, stream>>>(w_lin2, Bt2);
  prep_bt_kernel<<<dim3(1,128), 256, 0, stream>>>(w_mlp1, Bm1, 128, 128);
  prep_bt_kernel<<<dim3(1,64),  256, 0, stream>>>(w_mlp2, Bm2, 128, 128);

  // fused pointconv layers (XCD-swizzled gathers)
  fused_pc_kernel<264><<<PTS/64, 256, 0, stream>>>(fT1, xyz, knn, w_wn1, b_wn1, Bt1, b_lin1, fT2, 136);
  fused_pc_kernel<136><<<PTS/64, 256, 0, stream>>>(fT2, xyz, knn, w_wn2, b_wn2, Bt2, b_lin2, feat2, 128);

  // mlp1 128->128, mlp2 128->64 (f output), flow head
  mfma_lin_kernel<128,0><<<PTS/64, 256, 0, stream>>>(feat2, Bm1, b_mlp1, h1, 128, 0, 128);
  mfma_lin_kernel<64,1><<<PTS/64, 256, 0, stream>>>(h1, Bm2, b_mlp2, out, 128, 0, 0);
  flow_kernel<<<PTS/256, 256, 0, stream>>>(out, w_last, b_last, out + (long)4*64*NPTS);
}

// Round 10
// 309.835 us; speedup vs baseline: 2.4067x; 1.0676x over previous
//
#include <hip/hip_runtime.h>

#define NPTS 8192
#define PTS 32768

typedef unsigned short u16;
typedef __attribute__((ext_vector_type(8))) short bf16x8;
typedef __attribute__((ext_vector_type(4))) float f32x4;

__device__ __forceinline__ float lrelu(float x){ return x >= 0.f ? x : 0.1f*x; }
__device__ __forceinline__ unsigned f2bf(float x){
  unsigned u = __float_as_uint(x);
  return ((u + 0x7FFFu + ((u>>16)&1u)) >> 16);
}
__device__ __forceinline__ float bf2f(u16 h){ return __uint_as_float(((unsigned)h)<<16); }
__device__ __forceinline__ unsigned packbf(float x, float y){
  return f2bf(x) | (f2bf(y) << 16);
}
// D = S0.lo*S1.lo + S0.hi*S1.hi + S2  (bf16 pair dot, f32 accum) — CDNA VOP3P
__device__ __forceinline__ float dot2bf(unsigned f, unsigned w, float c){
  float d;
  asm("v_dot2_f32_bf16 %0, %1, %2, %3" : "=v"(d) : "v"(f), "v"(w), "v"(c));
  return d;
}

// ---- xyz fill: fT1 cols 0..2 + zero pad 259..263; fT2 cols 128..135 -------
__global__ __launch_bounds__(256) void xyz_fill_kernel(
    const float* __restrict__ xyz, u16* __restrict__ fT1, u16* __restrict__ fT2){
  long g = (long)blockIdx.x*256 + threadIdx.x;
  int b = (int)(g >> 13), n = (int)(g & 8191);
  unsigned v[3];
  #pragma unroll
  for (int j = 0; j < 3; ++j) v[j] = f2bf(xyz[((long)b*3 + j)*NPTS + n]);
  fT1[g*264 + 0] = (u16)v[0]; fT1[g*264 + 1] = (u16)v[1]; fT1[g*264 + 2] = (u16)v[2];
  #pragma unroll
  for (int j = 259; j < 264; ++j) fT1[g*264 + j] = 0;
  uint4 u;
  u.x = v[0] | (v[1] << 16);
  u.y = v[2];
  u.z = 0; u.w = 0;
  *(uint4*)(fT2 + g*136 + 128) = u;
}

// ---- transpose feat [B][256][N] -> fT1 rows [g][264] cols 3..258 (bf16) ----
__global__ __launch_bounds__(256) void transpose_feat_kernel(
    const float* __restrict__ feat, u16* __restrict__ fT1){
  __shared__ float tile[64][65];
  int bx = blockIdx.x, by = blockIdx.y, bz = blockIdx.z;
  int t = threadIdx.x;
  int x = t & 63, y4 = t >> 6;
  const float* src = feat + ((long)bz*256 + by*64)*NPTS + (long)bx*64;
  #pragma unroll
  for (int i = 0; i < 16; ++i){
    int c = y4 + i*4;
    tile[c][x] = src[(long)c*NPTS + x];
  }
  __syncthreads();
  u16* dst = fT1 + ((long)bz*NPTS + (long)bx*64)*264 + 3 + by*64;
  #pragma unroll
  for (int i = 0; i < 16; ++i){
    int p = y4 + i*4;
    dst[(long)p*264 + x] = (u16)f2bf(tile[x][p]);
  }
}

// ---- weight prep: Bt[o][k] bf16, zero-padded to KP -------------------------
__global__ void prep_bt_kernel(const float* __restrict__ W, u16* __restrict__ Bt,
                               int KP, int KREAL){
  int o = blockIdx.y;
  int k = blockIdx.x*256 + threadIdx.x;
  if (k < KP)
    Bt[(long)o*KP + k] = (k < KREAL) ? (u16)f2bf(W[(long)o*KREAL + k]) : (u16)0;
}

// layer2 channel permute: our c: 0..127 feat (ref c+3), 128..130 xyz (ref c-128)
__global__ void prep_bt2_kernel(const float* __restrict__ W, u16* __restrict__ Bt){
  int o = blockIdx.y;
  int k = blockIdx.x*256 + threadIdx.x;
  if (k >= 1088) return;
  int c = k >> 3, m = k & 7;
  u16 v = 0;
  if (c < 128)      v = (u16)f2bf(W[(long)o*1048 + (c+3)*8 + m]);
  else if (c < 131) v = (u16)f2bf(W[(long)o*1048 + (c-128)*8 + m]);
  Bt[(long)o*1088 + k] = v;
}

// ---- fused PointConv v3: wave-local stage/agg, dot2, 1 barrier/chunk -------
// Block: 64 points x 128 outs, 4 waves; wave w owns points [16w,16w+16).
// fst/wk LDS: packed bf16 k-pairs, u32 word layouts [p][c][kp] / [p][m][kp],
// point stride 68 words (bank stagger). As double-buffered (MFMA operand).
// B-fragments read directly from L2 (no Bs). 53.2 KB LDS -> 3 blocks/CU.
template<int S>
__global__ __launch_bounds__(256, 3) void fused_pc3_kernel(
    const u16* __restrict__ fT, const float* __restrict__ xyz,
    const int* __restrict__ knn, const float* __restrict__ w_wn,
    const float* __restrict__ b_wn, const u16* __restrict__ Bt,
    const float* __restrict__ bias, u16* __restrict__ outp, int out_stride){
  constexpr int K   = S*8;
  constexpr int NCH = S/8;
  __shared__ __align__(16) unsigned fstw[64*68];   // 17408 B
  __shared__ __align__(16) unsigned wkw[64*68];    // 17408 B
  __shared__ __align__(16) u16 As[2][64][72];      // 18432 B

  int t = threadIdx.x;
  int cpx = (int)(gridDim.x >> 3);
  int swz = ((int)blockIdx.x & 7)*cpx + ((int)blockIdx.x >> 3);
  int m0 = swz*64;
  int b = m0 >> 13;
  int bbase = b << 13;
  int n0 = m0 & 8191;
  int w = t >> 6, l = t & 63;
  int ln = l & 15, lh = l >> 4;
  int oc0 = w*32;
  int p  = w*16 + (l >> 2);   // this thread's point (stage + phaseA + wk)
  int kq = l & 3;             // staging k-quad / phase-A channel pair

  // ---- knn quad + gather byte offsets ----
  int4 iv = *(const int4*)(knn + ((long)(bbase + n0 + p))*16 + kq*4);
  unsigned offs[4];
  offs[0] = (unsigned)((bbase + iv.x)*S*2);
  offs[1] = (unsigned)((bbase + iv.y)*S*2);
  offs[2] = (unsigned)((bbase + iv.z)*S*2);
  offs[3] = (unsigned)((bbase + iv.w)*S*2);

  // ---- prefetch chunk-0 gathers ----
  uint4 ga[4];
  #pragma unroll
  for (int j = 0; j < 4; ++j)
    ga[j] = *(const uint4*)((const char*)fT + offs[j]);

  // ---- weight-net: wk packed pairs -> wkw[p][m][2kq..2kq+1] (wave-local) ----
  {
    float cx = xyz[((long)b*3+0)*NPTS + n0 + p];
    float cy = xyz[((long)b*3+1)*NPTS + n0 + p];
    float cz = xyz[((long)b*3+2)*NPTS + n0 + p];
    float wm[8][3], bm[8];
    #pragma unroll
    for (int m = 0; m < 8; ++m){
      wm[m][0] = w_wn[m*3+0]; wm[m][1] = w_wn[m*3+1]; wm[m][2] = w_wn[m*3+2];
      bm[m] = b_wn[m];
    }
    float wv[4][8];
    int idq[4] = {iv.x, iv.y, iv.z, iv.w};
    #pragma unroll
    for (int j = 0; j < 4; ++j){
      int id = idq[j];
      float px = xyz[((long)b*3+0)*NPTS + id] - cx;
      float py = xyz[((long)b*3+1)*NPTS + id] - cy;
      float pz = xyz[((long)b*3+2)*NPTS + id] - cz;
      #pragma unroll
      for (int m = 0; m < 8; ++m)
        wv[j][m] = lrelu(wm[m][0]*px + wm[m][1]*py + wm[m][2]*pz + bm[m]);
    }
    #pragma unroll
    for (int m = 0; m < 8; ++m){
      uint2 u;
      u.x = packbf(wv[0][m], wv[1][m]);   // kp = 2kq   (k even|odd)
      u.y = packbf(wv[2][m], wv[3][m]);   // kp = 2kq+1
      *(uint2*)&wkw[p*68 + m*8 + kq*2] = u;
    }
  }

  f32x4 acc[4][2];
  #pragma unroll
  for (int i = 0; i < 4; ++i)
    #pragma unroll
    for (int j = 0; j < 2; ++j) acc[i][j] = (f32x4){0.f,0.f,0.f,0.f};

  for (int ch = 0; ch < NCH; ++ch){
    // ---- stage fst (wave-local): pack k-pairs via v_perm ----
    #pragma unroll
    for (int wd = 0; wd < 4; ++wd){
      unsigned a0 = ((const unsigned*)&ga[0])[wd];
      unsigned b0 = ((const unsigned*)&ga[1])[wd];
      unsigned c0 = ((const unsigned*)&ga[2])[wd];
      unsigned d0 = ((const unsigned*)&ga[3])[wd];
      uint2 ue, uo;
      ue.x = __builtin_amdgcn_perm(b0, a0, 0x05040100);  // ch 2wd,   kp 2kq
      ue.y = __builtin_amdgcn_perm(d0, c0, 0x05040100);  // ch 2wd,   kp 2kq+1
      uo.x = __builtin_amdgcn_perm(b0, a0, 0x07060302);  // ch 2wd+1, kp 2kq
      uo.y = __builtin_amdgcn_perm(d0, c0, 0x07060302);
      *(uint2*)&fstw[p*68 + (2*wd)*8   + kq*2] = ue;
      *(uint2*)&fstw[p*68 + (2*wd+1)*8 + kq*2] = uo;
    }
    // ---- prefetch next chunk's gathers ----
    if (ch + 1 < NCH){
      #pragma unroll
      for (int j = 0; j < 4; ++j)
        ga[j] = *(const uint4*)((const char*)fT + offs[j] + (ch+1)*16);
    }
    // ---- prefetch B fragments direct from L2 ----
    uint4 bfr[2][2];
    #pragma unroll
    for (int kk = 0; kk < 2; ++kk)
      #pragma unroll
      for (int fn = 0; fn < 2; ++fn)
        bfr[kk][fn] = *(const uint4*)(Bt + (long)(oc0 + fn*16 + ln)*K + ch*64 + kk*32 + lh*8);

    // ---- phase A: 2 channels x 8 m via dot2 chains (wave-local reads) ----
    int par = ch & 1;
    {
      int c0 = kq*2;
      uint4 f0a = *(const uint4*)&fstw[p*68 + c0*8 + 0];
      uint4 f0b = *(const uint4*)&fstw[p*68 + c0*8 + 4];
      uint4 f1a = *(const uint4*)&fstw[p*68 + (c0+1)*8 + 0];
      uint4 f1b = *(const uint4*)&fstw[p*68 + (c0+1)*8 + 4];
      float a0[8], a1[8];
      #pragma unroll
      for (int m = 0; m < 8; ++m){
        uint4 wa = *(const uint4*)&wkw[p*68 + m*8 + 0];
        uint4 wb = *(const uint4*)&wkw[p*68 + m*8 + 4];
        float s0 = 0.f, s1 = 0.f;
        s0 = dot2bf(f0a.x, wa.x, s0); s1 = dot2bf(f1a.x, wa.x, s1);
        s0 = dot2bf(f0a.y, wa.y, s0); s1 = dot2bf(f1a.y, wa.y, s1);
        s0 = dot2bf(f0a.z, wa.z, s0); s1 = dot2bf(f1a.z, wa.z, s1);
        s0 = dot2bf(f0a.w, wa.w, s0); s1 = dot2bf(f1a.w, wa.w, s1);
        s0 = dot2bf(f0b.x, wb.x, s0); s1 = dot2bf(f1b.x, wb.x, s1);
        s0 = dot2bf(f0b.y, wb.y, s0); s1 = dot2bf(f1b.y, wb.y, s1);
        s0 = dot2bf(f0b.z, wb.z, s0); s1 = dot2bf(f1b.z, wb.z, s1);
        s0 = dot2bf(f0b.w, wb.w, s0); s1 = dot2bf(f1b.w, wb.w, s1);
        a0[m] = s0; a1[m] = s1;
      }
      uint4 u0, u1;
      u0.x = packbf(a0[0], a0[1]); u0.y = packbf(a0[2], a0[3]);
      u0.z = packbf(a0[4], a0[5]); u0.w = packbf(a0[6], a0[7]);
      u1.x = packbf(a1[0], a1[1]); u1.y = packbf(a1[2], a1[3]);
      u1.z = packbf(a1[4], a1[5]); u1.w = packbf(a1[6], a1[7]);
      *(uint4*)&As[par][p][kq*16 + 0] = u0;
      *(uint4*)&As[par][p][kq*16 + 8] = u1;
    }
    __syncthreads();   // As[par] complete across waves

    // ---- MFMA on the chunk (B from regs) ----
    __builtin_amdgcn_s_setprio(1);
    #pragma unroll
    for (int kk = 0; kk < 2; ++kk){
      int koff = kk*32 + lh*8;
      bf16x8 af[4];
      #pragma unroll
      for (int fm = 0; fm < 4; ++fm)
        af[fm] = *(const bf16x8*)&As[par][fm*16 + ln][koff];
      #pragma unroll
      for (int fn = 0; fn < 2; ++fn){
        bf16x8 bfrag = *(const bf16x8*)&bfr[kk][fn];
        #pragma unroll
        for (int fm = 0; fm < 4; ++fm)
          acc[fm][fn] = __builtin_amdgcn_mfma_f32_16x16x32_bf16(af[fm], bfrag, acc[fm][fn], 0, 0, 0);
      }
    }
    __builtin_amdgcn_s_setprio(0);
  }

  // ---- epilogue (Cs aliases fstw) ----
  u16* Cs = (u16*)fstw;
  float bia[2] = { bias[oc0 + ln], bias[oc0 + 16 + ln] };
  #pragma unroll
  for (int fm = 0; fm < 4; ++fm)
    #pragma unroll
    for (int fn = 0; fn < 2; ++fn)
      #pragma unroll
      for (int r = 0; r < 4; ++r){
        int row = fm*16 + lh*4 + r;
        int col = oc0 + fn*16 + ln;
        Cs[row*128 + col] = (u16)f2bf(lrelu(acc[fm][fn][r] + bia[fn]));
      }
  __syncthreads();
  int r2 = t >> 2, s2 = t & 3;
  u16* dst = outp + (long)(m0 + r2)*out_stride + s2*32;
  #pragma unroll
  for (int q = 0; q < 4; ++q)
    *(uint4*)(dst + q*8) = *(uint4*)&Cs[r2*128 + s2*32 + q*8];
}

// ---- MFMA GEMM (round-3 verified): used for mlp1/mlp2 ----------------------
template<int BN, int OUTMODE>
__global__ __launch_bounds__(256) void mfma_lin_kernel(
    const u16* __restrict__ A, const u16* __restrict__ Bt,
    const float* __restrict__ bias, void* __restrict__ outp,
    int K, long chunk_base, int out_stride){
  __shared__ __align__(16) u16 As[64][72];
  __shared__ __align__(16) u16 Bs[BN][72];
  constexpr int FM = (BN == 128) ? 4 : 2;
  int t = threadIdx.x;
  int w = t >> 6, l = t & 63;
  int ln = l & 15, lh = l >> 4;
  int m0 = blockIdx.x * 64;
  int MOFF = (BN == 128) ? 0 : (w >> 1)*32;
  int o0   = (BN == 128) ? w*32 : (w & 1)*32;
  int srow = t >> 3;
  int scol = (t & 7) * 8;

  f32x4 acc[FM][2];
  #pragma unroll
  for (int i = 0; i < FM; ++i)
    #pragma unroll
    for (int j = 0; j < 2; ++j) acc[i][j] = (f32x4){0.f,0.f,0.f,0.f};

  int nkc = K >> 6;
  for (int kc = 0; kc < nkc; ++kc){
    uint4 a0 = *(const uint4*)(A + (long)(m0 + srow)*K      + kc*64 + scol);
    uint4 a1 = *(const uint4*)(A + (long)(m0 + srow + 32)*K + kc*64 + scol);
    uint4 bv[BN/32];
    #pragma unroll
    for (int r = 0; r < BN/32; ++r)
      bv[r] = *(const uint4*)(Bt + (long)(srow + r*32)*K + kc*64 + scol);
    __syncthreads();
    *(uint4*)&As[srow][scol]      = a0;
    *(uint4*)&As[srow + 32][scol] = a1;
    #pragma unroll
    for (int r = 0; r < BN/32; ++r)
      *(uint4*)&Bs[srow + r*32][scol] = bv[r];
    __syncthreads();
    #pragma unroll
    for (int kk = 0; kk < 2; ++kk){
      int koff = kk*32 + lh*8;
      bf16x8 af[FM], bfr[2];
      #pragma unroll
      for (int fm = 0; fm < FM; ++fm)
        af[fm] = *(const bf16x8*)&As[MOFF + fm*16 + ln][koff];
      #pragma unroll
      for (int fn = 0; fn < 2; ++fn)
        bfr[fn] = *(const bf16x8*)&Bs[o0 + fn*16 + ln][koff];
      #pragma unroll
      for (int fm = 0; fm < FM; ++fm)
        #pragma unroll
        for (int fn = 0; fn < 2; ++fn)
          acc[fm][fn] = __builtin_amdgcn_mfma_f32_16x16x32_bf16(af[fm], bfr[fn], acc[fm][fn], 0, 0, 0);
    }
    __syncthreads();
  }

  if (OUTMODE == 0){
    __shared__ u16 Cs[64*128];
    float bia[2];
    #pragma unroll
    for (int fn = 0; fn < 2; ++fn) bia[fn] = bias[o0 + fn*16 + ln];
    __syncthreads();
    #pragma unroll
    for (int fm = 0; fm < FM; ++fm)
      #pragma unroll
      for (int fn = 0; fn < 2; ++fn)
        #pragma unroll
        for (int r = 0; r < 4; ++r){
          int row = MOFF + fm*16 + lh*4 + r;
          int col = o0 + fn*16 + ln;
          Cs[row*128 + col] = (u16)f2bf(lrelu(acc[fm][fn][r] + bia[fn]));
        }
    __syncthreads();
    int r2 = t >> 2, s2 = t & 3;
    u16* dst = (u16*)outp + (chunk_base + m0 + r2)*(long)out_stride + s2*32;
    #pragma unroll
    for (int q = 0; q < 4; ++q)
      *(uint4*)(dst + q*8) = *(uint4*)&Cs[r2*128 + s2*32 + q*8];
  } else {
    float* outf = (float*)outp;
    #pragma unroll
    for (int fm = 0; fm < FM; ++fm)
      #pragma unroll
      for (int fn = 0; fn < 2; ++fn){
        long gp = chunk_base + m0 + MOFF + fm*16 + lh*4;
        int bb = (int)(gp >> 13), nn = (int)(gp & 8191);
        int col = o0 + fn*16 + ln;
        float bia = bias[col];
        float4 v;
        v.x = lrelu(acc[fm][fn][0] + bia);
        v.y = lrelu(acc[fm][fn][1] + bia);
        v.z = lrelu(acc[fm][fn][2] + bia);
        v.w = lrelu(acc[fm][fn][3] + bia);
        *(float4*)(outf + ((long)(bb*64 + col) << 13) + nn) = v;
      }
  }
}

// ---- flow head: [3][64] @ f ------------------------------------------------
__global__ __launch_bounds__(256) void flow_kernel(
    const float* __restrict__ f, const float* __restrict__ W,
    const float* __restrict__ bias, float* __restrict__ flow){
  long g = (long)blockIdx.x*256 + threadIdx.x;
  int b = (int)(g >> 13), n = (int)(g & 8191);
  float a0 = bias[0], a1 = bias[1], a2 = bias[2];
  const float* fb = f + (long)b*64*NPTS + n;
  #pragma unroll
  for (int c = 0; c < 64; ++c){
    float v = fb[(long)c*NPTS];
    a0 += v * W[c];
    a1 += v * W[64 + c];
    a2 += v * W[128 + c];
  }
  flow[((long)b*3 + 0)*NPTS + n] = a0;
  flow[((long)b*3 + 1)*NPTS + n] = a1;
  flow[((long)b*3 + 2)*NPTS + n] = a2;
}

extern "C" void kernel_launch(void* const* d_in, const int* in_sizes, int n_in,
                              void* d_out, int out_size, void* d_ws, size_t ws_size,
                              hipStream_t stream){
  const float* xyz    = (const float*)d_in[0];
  const float* feat   = (const float*)d_in[1];
  const int*   knn    = (const int*)  d_in[2];
  const float* w_wn1  = (const float*)d_in[3];
  const float* b_wn1  = (const float*)d_in[4];
  const float* w_lin1 = (const float*)d_in[5];
  const float* b_lin1 = (const float*)d_in[6];
  const float* w_wn2  = (const float*)d_in[7];
  const float* b_wn2  = (const float*)d_in[8];
  const float* w_lin2 = (const float*)d_in[9];
  const float* b_lin2 = (const float*)d_in[10];
  const float* w_mlp1 = (const float*)d_in[11];
  const float* b_mlp1 = (const float*)d_in[12];
  const float* w_mlp2 = (const float*)d_in[13];
  const float* b_mlp2 = (const float*)d_in[14];
  const float* w_last = (const float*)d_in[15];
  const float* b_last = (const float*)d_in[16];
  float* out = (float*)d_out;

  char* p = (char*)d_ws;
  auto carve = [&](size_t bytes)->char*{
    char* r = p; p += (bytes + 255) & ~(size_t)255; return r;
  };
  u16* fT1   = (u16*)carve((size_t)PTS*264*2);
  u16* fT2   = (u16*)carve((size_t)PTS*136*2);
  u16* Bt1   = (u16*)carve((size_t)128*2112*2);
  u16* Bt2   = (u16*)carve((size_t)128*1088*2);
  u16* Bm1   = (u16*)carve((size_t)128*128*2);
  u16* Bm2   = (u16*)carve((size_t)64*128*2);
  u16* feat2 = (u16*)carve((size_t)PTS*128*2);
  u16* h1    = (u16*)carve((size_t)PTS*128*2);

  xyz_fill_kernel<<<PTS/256, 256, 0, stream>>>(xyz, fT1, fT2);
  transpose_feat_kernel<<<dim3(128,4,4), 256, 0, stream>>>(feat, fT1);
  prep_bt_kernel<<<dim3(9,128), 256, 0, stream>>>(w_lin1, Bt1, 2112, 2072);
  prep_bt2_kernel<<<dim3(5,128), 256, 0, stream>>>(w_lin2, Bt2);
  prep_bt_kernel<<<dim3(1,128), 256, 0, stream>>>(w_mlp1, Bm1, 128, 128);
  prep_bt_kernel<<<dim3(1,64),  256, 0, stream>>>(w_mlp2, Bm2, 128, 128);

  // fused pointconv layers (wave-local v3, XCD-swizzled)
  fused_pc3_kernel<264><<<PTS/64, 256, 0, stream>>>(fT1, xyz, knn, w_wn1, b_wn1, Bt1, b_lin1, fT2, 136);
  fused_pc3_kernel<136><<<PTS/64, 256, 0, stream>>>(fT2, xyz, knn, w_wn2, b_wn2, Bt2, b_lin2, feat2, 128);

  // mlp1 128->128, mlp2 128->64 (f output), flow head
  mfma_lin_kernel<128,0><<<PTS/64, 256, 0, stream>>>(feat2, Bm1, b_mlp1, h1, 128, 0, 128);
  mfma_lin_kernel<64,1><<<PTS/64, 256, 0, stream>>>(h1, Bm2, b_mlp2, out, 128, 0, 0);
  flow_kernel<<<PTS/256, 256, 0, stream>>>(out, w_last, b_last, out + (long)4*64*NPTS);
}